// Round 13
// baseline (437.266 us; speedup 1.0000x reference)
//
#include <hip/hip_runtime.h>
#include <hip/hip_bf16.h>
#include <hip/hip_cooperative_groups.h>

namespace cg = cooperative_groups;

#define CH 64          // IN_C = HID_C = OUT_C = 64
#define BSH 9          // bucket shift: 512 nodes/bucket
#define CHUNK 16384    // edges per block in hist/scatter passes (1024 thr x 16)
#define MAXB 10240     // LDS col buffer (edges/bucket ~8163 +- 90)
#define NREP 4         // LDS histogram replicas (quarter-block each)
#define RPAD 257       // replica stride: 257 ints rotates bank mapping
// pairs packing: src < 2^17 (N=100000 <= 131072), dstLocal < 2^9 -> 26 bits
//
// SESSION LEDGER (hard-won):
//  R1/R2: 25k global atomicAdds to ONE cache line serialize cross-XCD = +276us.
//  R4:    in-wave GEMM via shfl+LDS: DS-pipe chains poison gather epilogues.
//  R7:    serial load-rounds are the gather lever at constant load count.
//  R8/R9: hist replication helps; scans must be chain-free (wide batches).
//  R10/R11/R12: FETCH tracks cache-LINE touches: a 4B misalignment of xws
//         made every 128B row straddle 2 lines (88->157MB).  ALIGNMENT RULE:
//         any workspace change must re-verify 128B alignment of row buffers.
//  R13:   this round — budget audit: explained work ~155us vs 265 measured.
//         Residual ~100us is either per-launch overhead (x10 kernels) or a
//         CSR/GEMM kernel hiding just under the 42us top-5 cutoff.  Fusing
//         kernels discriminates: 10 -> 6 launches via two cooperative
//         kernels (csr_coop = 4 proven phases + grid.sync; norm_coop =
//         reduce+norm).  grid.sync carries device-scope fencing (cross-XCD).
//  prev:  scalar s_load of col regressed; serial nodes/wave regressed 2.3x.

// ---------- CSR build: ONE cooperative kernel, 4 grid-synced phases ----------
// smem aliased across phases; max = bucket phase 3*512+MAXB = 11776 ints (47KB).
// Grid = nb (196) blocks x 1024 thr -> 1 block/CU co-residency (196 <= 256).

__global__ __launch_bounds__(1024)
void csr_coop_kernel(const int* __restrict__ src, const int* __restrict__ dst,
                     int* __restrict__ blockHist, int* __restrict__ bucketStart,
                     unsigned* __restrict__ pairs, int* __restrict__ col,
                     int* __restrict__ rs, float* __restrict__ dis,
                     int N, int nb, int E, int nblkE) {
    cg::grid_group grid = cg::this_grid();
    __shared__ int smem[3 * 512 + MAXB];   // 11776 ints
    int t = threadIdx.x;
    int nvblk = nblkE * NREP;

    // ---- phase 1: coarse histogram (blocks 0..nblkE-1), 4x replicated ----
    if ((int)blockIdx.x < nblkE) {
        int* h = smem;                      // NREP*RPAD = 4112 ints
        int rep = t >> 8;
        for (int i = t; i < NREP * RPAD; i += 1024) h[i] = 0;
        __syncthreads();
        int* hr = h + rep * RPAD;
        int base = blockIdx.x * CHUNK + t * 16;
#pragma unroll
        for (int j = 0; j < 16; j += 4) {
            int e = base + j;
            if (e + 3 < E) {
                int4 d = *(const int4*)(dst + e);
                atomicAdd(&hr[d.x >> BSH], 1);
                atomicAdd(&hr[d.y >> BSH], 1);
                atomicAdd(&hr[d.z >> BSH], 1);
                atomicAdd(&hr[d.w >> BSH], 1);
            } else {
                for (int k = e; k < E && k < e + 4; ++k) atomicAdd(&hr[dst[k] >> BSH], 1);
            }
        }
        __syncthreads();
        for (int r = 0; r < NREP; ++r)
            for (int i = t; i < nb; i += 1024)
                blockHist[(blockIdx.x * NREP + r) * nb + i] = h[r * RPAD + i];
    }
    grid.sync();

    // ---- phase 2: scan (block 0; R12-proven 4-group + 16-wide + LDS scan) ----
    if (blockIdx.x == 0) {
        int* qsum = smem;          // NREP*256
        int* tots = smem + 1024;   // 256
        int* offs = smem + 1280;   // 256
        int g = t >> 8;
        int b = t & 255;
        int qlen = nvblk / NREP;
        int q0 = g * qlen;
        int q1 = (g == NREP - 1) ? nvblk : q0 + qlen;
        int s = 0;
        if (b < nb) {
            int blk = q0;
            for (; blk + 16 <= q1; blk += 16) {
                int v0 = blockHist[(blk + 0) * nb + b];
                int v1 = blockHist[(blk + 1) * nb + b];
                int v2 = blockHist[(blk + 2) * nb + b];
                int v3 = blockHist[(blk + 3) * nb + b];
                int v4 = blockHist[(blk + 4) * nb + b];
                int v5 = blockHist[(blk + 5) * nb + b];
                int v6 = blockHist[(blk + 6) * nb + b];
                int v7 = blockHist[(blk + 7) * nb + b];
                int v8 = blockHist[(blk + 8) * nb + b];
                int v9 = blockHist[(blk + 9) * nb + b];
                int va = blockHist[(blk + 10) * nb + b];
                int vb = blockHist[(blk + 11) * nb + b];
                int vc = blockHist[(blk + 12) * nb + b];
                int vd = blockHist[(blk + 13) * nb + b];
                int ve = blockHist[(blk + 14) * nb + b];
                int vf = blockHist[(blk + 15) * nb + b];
                s += v0 + v1 + v2 + v3 + v4 + v5 + v6 + v7
                   + v8 + v9 + va + vb + vc + vd + ve + vf;
            }
            for (; blk < q1; ++blk) s += blockHist[blk * nb + b];
        }
        qsum[g * 256 + b] = s;
        __syncthreads();
        if (t < 256) {
            tots[t] = qsum[t] + qsum[256 + t] + qsum[512 + t] + qsum[768 + t];
            offs[t] = tots[t];
        }
        __syncthreads();
        for (int off = 1; off < 256; off <<= 1) {
            int a = (t < 256 && t >= off) ? offs[t - off] : 0;
            __syncthreads();
            if (t < 256) offs[t] += a;
            __syncthreads();
        }
        if (b < nb) {
            int r = offs[b] - tots[b];
            for (int gg = 0; gg < g; ++gg) r += qsum[gg * 256 + b];
            int blk = q0;
            for (; blk + 16 <= q1; blk += 16) {
                int v0 = blockHist[(blk + 0) * nb + b];
                int v1 = blockHist[(blk + 1) * nb + b];
                int v2 = blockHist[(blk + 2) * nb + b];
                int v3 = blockHist[(blk + 3) * nb + b];
                int v4 = blockHist[(blk + 4) * nb + b];
                int v5 = blockHist[(blk + 5) * nb + b];
                int v6 = blockHist[(blk + 6) * nb + b];
                int v7 = blockHist[(blk + 7) * nb + b];
                int v8 = blockHist[(blk + 8) * nb + b];
                int v9 = blockHist[(blk + 9) * nb + b];
                int va = blockHist[(blk + 10) * nb + b];
                int vb = blockHist[(blk + 11) * nb + b];
                int vc = blockHist[(blk + 12) * nb + b];
                int vd = blockHist[(blk + 13) * nb + b];
                int ve = blockHist[(blk + 14) * nb + b];
                int vf = blockHist[(blk + 15) * nb + b];
                blockHist[(blk + 0) * nb + b] = r; r += v0;
                blockHist[(blk + 1) * nb + b] = r; r += v1;
                blockHist[(blk + 2) * nb + b] = r; r += v2;
                blockHist[(blk + 3) * nb + b] = r; r += v3;
                blockHist[(blk + 4) * nb + b] = r; r += v4;
                blockHist[(blk + 5) * nb + b] = r; r += v5;
                blockHist[(blk + 6) * nb + b] = r; r += v6;
                blockHist[(blk + 7) * nb + b] = r; r += v7;
                blockHist[(blk + 8) * nb + b] = r; r += v8;
                blockHist[(blk + 9) * nb + b] = r; r += v9;
                blockHist[(blk + 10) * nb + b] = r; r += va;
                blockHist[(blk + 11) * nb + b] = r; r += vb;
                blockHist[(blk + 12) * nb + b] = r; r += vc;
                blockHist[(blk + 13) * nb + b] = r; r += vd;
                blockHist[(blk + 14) * nb + b] = r; r += ve;
                blockHist[(blk + 15) * nb + b] = r; r += vf;
            }
            for (; blk < q1; ++blk) {
                int v = blockHist[blk * nb + b];
                blockHist[blk * nb + b] = r;
                r += v;
            }
        }
        if (t <= nb) bucketStart[t] = offs[t] - tots[t];  // tots=0 for t>=nb
    }
    grid.sync();

    // ---- phase 3: scatter pairs (blocks 0..nblkE-1), per-replica cursors ----
    if ((int)blockIdx.x < nblkE) {
        int* cur = smem;
        int rep = t >> 8;
        for (int r = 0; r < NREP; ++r)
            for (int i = t; i < nb; i += 1024)
                cur[r * RPAD + i] = blockHist[(blockIdx.x * NREP + r) * nb + i];
        __syncthreads();
        int* cr = cur + rep * RPAD;
        int base = blockIdx.x * CHUNK + t * 16;
#pragma unroll
        for (int j = 0; j < 16; j += 4) {
            int e = base + j;
            if (e + 3 < E) {
                int4 d = *(const int4*)(dst + e);
                int4 s = *(const int4*)(src + e);
                int p0 = atomicAdd(&cr[d.x >> BSH], 1);
                pairs[p0] = ((unsigned)(d.x & 511) << 17) | (unsigned)s.x;
                int p1 = atomicAdd(&cr[d.y >> BSH], 1);
                pairs[p1] = ((unsigned)(d.y & 511) << 17) | (unsigned)s.y;
                int p2 = atomicAdd(&cr[d.z >> BSH], 1);
                pairs[p2] = ((unsigned)(d.z & 511) << 17) | (unsigned)s.z;
                int p3 = atomicAdd(&cr[d.w >> BSH], 1);
                pairs[p3] = ((unsigned)(d.w & 511) << 17) | (unsigned)s.w;
            } else {
                for (int k = e; k < E && k < e + 4; ++k) {
                    int d = dst[k];
                    int p = atomicAdd(&cr[d >> BSH], 1);
                    pairs[p] = ((unsigned)(d & 511) << 17) | (unsigned)src[k];
                }
            }
        }
    }
    grid.sync();

    // ---- phase 4: per-bucket counting sort -> col/rs/dis (all nb blocks) ----
    {
        int* hist   = smem;           // 512
        int* offs   = smem + 512;     // 512
        int* cursor = smem + 1024;    // 512
        int* lcol   = smem + 1536;    // MAXB
        int b = blockIdx.x;
        int n0 = b << BSH;
        int nn = min(512, N - n0);
        int start = bucketStart[b];
        int endp = bucketStart[b + 1];
        int cnt = endp - start;
        bool big = cnt > MAXB;  // safety fallback: direct col writes
        for (int i = t; i < nn; i += 1024) hist[i] = 0;
        __syncthreads();
        for (int i = start + t; i < endp; i += 1024) {
            unsigned p = pairs[i];
            atomicAdd(&hist[p >> 17], 1);
        }
        __syncthreads();
        if (t < 512) offs[t] = (t < nn) ? hist[t] : 0;
        __syncthreads();
        for (int off = 1; off < 512; off <<= 1) {
            int a = (t < 512 && t >= off) ? offs[t - off] : 0;
            __syncthreads();
            if (t < 512) offs[t] += a;
            __syncthreads();
        }
        if (t < nn) {
            int excl = offs[t] - hist[t];          // exclusive scan value
            rs[n0 + t] = start + excl;
            dis[n0 + t] = rsqrtf((float)hist[t] + 1.0f);
            cursor[t] = excl;
        }
        if (b == 0 && t == 0) rs[N] = E;           // branchless gather end
        __syncthreads();
        for (int i = start + t; i < endp; i += 1024) {
            unsigned p = pairs[i];
            int pos = atomicAdd(&cursor[p >> 17], 1);
            int sv = (int)(p & 0x1FFFFu);
            if (big) col[start + pos] = sv;
            else lcol[pos] = sv;
        }
        __syncthreads();
        if (!big) {
            for (int i = t; i < cnt; i += 1024) col[start + i] = lcol[i];
        }
    }
}

// ---------- compute ----------

__device__ inline unsigned pack_bf2(float a, float b) {
    __hip_bfloat162 t;
    t.x = __float2bfloat16(a);
    t.y = __float2bfloat16(b);
    unsigned u;
    __builtin_memcpy(&u, &t, 4);
    return u;
}

__device__ inline float bf_lo(unsigned u) {
    unsigned w = u << 16; float f; __builtin_memcpy(&f, &w, 4); return f;
}
__device__ inline float bf_hi(unsigned u) {
    unsigned w = u & 0xffff0000u; float f; __builtin_memcpy(&f, &w, 4); return f;
}

// uniform-base + 32-bit byte-offset load -> global_load_dword v, voff, s[base]
__device__ inline unsigned ldu(const unsigned* p, unsigned boff) {
    return *(const unsigned*)((const char*)p + boff);
}

#define FMA32(x0, x1, x2, x3, wa, wb)                                        \
    a00 += (x0) * (wa).x; a01 += (x0) * (wa).y;                              \
    a02 += (x0) * (wa).z; a03 += (x0) * (wa).w;                              \
    a04 += (x0) * (wb).x; a05 += (x0) * (wb).y;                              \
    a06 += (x0) * (wb).z; a07 += (x0) * (wb).w;                              \
    a10 += (x1) * (wa).x; a11 += (x1) * (wa).y;                              \
    a12 += (x1) * (wa).z; a13 += (x1) * (wa).w;                              \
    a14 += (x1) * (wb).x; a15 += (x1) * (wb).y;                              \
    a16 += (x1) * (wb).z; a17 += (x1) * (wb).w;                              \
    a20 += (x2) * (wa).x; a21 += (x2) * (wa).y;                              \
    a22 += (x2) * (wa).z; a23 += (x2) * (wa).w;                              \
    a24 += (x2) * (wb).x; a25 += (x2) * (wb).y;                              \
    a26 += (x2) * (wb).z; a27 += (x2) * (wb).w;                              \
    a30 += (x3) * (wa).x; a31 += (x3) * (wa).y;                              \
    a32 += (x3) * (wa).z; a33 += (x3) * (wa).w;                              \
    a34 += (x3) * (wb).x; a35 += (x3) * (wb).y;                              \
    a36 += (x3) * (wb).z; a37 += (x3) * (wb).w;

// GEMM: 4 rows x 8 cols per thread (R1-R12: correctness-proven).  All named
// scalars.  unroll 2 under the 128-VGPR cap of (256,4).
__global__ __launch_bounds__(256, 4)
void gemm64_scaled_kernel(const float* __restrict__ X, const float* __restrict__ W,
                          const float* __restrict__ dis,
                          __hip_bfloat16* __restrict__ Y, int n) {
    __shared__ float Ws[CH * CH];
    {
        float4* w4 = (float4*)Ws;
        const float4* g4 = (const float4*)W;
        for (int i = threadIdx.x; i < CH * CH / 4; i += 256) w4[i] = g4[i];
    }
    __syncthreads();
    int t = threadIdx.x;
    int cbase = (t & 7) * 8;
    int r0 = blockIdx.x * 128 + (t >> 3) * 4;
    if (r0 >= n) return;
    int rB = min(r0 + 1, n - 1);
    int rC = min(r0 + 2, n - 1);
    int rD = min(r0 + 3, n - 1);
    const float4* pA = (const float4*)(X + (size_t)r0 * CH);
    const float4* pB = (const float4*)(X + (size_t)rB * CH);
    const float4* pC = (const float4*)(X + (size_t)rC * CH);
    const float4* pD = (const float4*)(X + (size_t)rD * CH);

    float a00 = 0.f, a01 = 0.f, a02 = 0.f, a03 = 0.f;
    float a04 = 0.f, a05 = 0.f, a06 = 0.f, a07 = 0.f;
    float a10 = 0.f, a11 = 0.f, a12 = 0.f, a13 = 0.f;
    float a14 = 0.f, a15 = 0.f, a16 = 0.f, a17 = 0.f;
    float a20 = 0.f, a21 = 0.f, a22 = 0.f, a23 = 0.f;
    float a24 = 0.f, a25 = 0.f, a26 = 0.f, a27 = 0.f;
    float a30 = 0.f, a31 = 0.f, a32 = 0.f, a33 = 0.f;
    float a34 = 0.f, a35 = 0.f, a36 = 0.f, a37 = 0.f;

#pragma unroll 2
    for (int k4 = 0; k4 < CH / 4; ++k4) {
        float4 xa = pA[k4];
        float4 xb = pB[k4];
        float4 xc = pC[k4];
        float4 xd = pD[k4];
        const float* wr = &Ws[(k4 * 4) * CH + cbase];
        float4 wa, wb;
        wa = *(const float4*)(wr);
        wb = *(const float4*)(wr + 4);
        FMA32(xa.x, xb.x, xc.x, xd.x, wa, wb)
        wa = *(const float4*)(wr + CH);
        wb = *(const float4*)(wr + CH + 4);
        FMA32(xa.y, xb.y, xc.y, xd.y, wa, wb)
        wa = *(const float4*)(wr + 2 * CH);
        wb = *(const float4*)(wr + 2 * CH + 4);
        FMA32(xa.z, xb.z, xc.z, xd.z, wa, wb)
        wa = *(const float4*)(wr + 3 * CH);
        wb = *(const float4*)(wr + 3 * CH + 4);
        FMA32(xa.w, xb.w, xc.w, xd.w, wa, wb)
    }

    uint4 pk;
    float d0 = dis[r0];
    pk.x = pack_bf2(a00 * d0, a01 * d0);
    pk.y = pack_bf2(a02 * d0, a03 * d0);
    pk.z = pack_bf2(a04 * d0, a05 * d0);
    pk.w = pack_bf2(a06 * d0, a07 * d0);
    *(uint4*)(Y + (size_t)r0 * CH + cbase) = pk;
    if (r0 + 1 < n) {
        float d1 = dis[r0 + 1];
        pk.x = pack_bf2(a10 * d1, a11 * d1);
        pk.y = pack_bf2(a12 * d1, a13 * d1);
        pk.z = pack_bf2(a14 * d1, a15 * d1);
        pk.w = pack_bf2(a16 * d1, a17 * d1);
        *(uint4*)(Y + (size_t)(r0 + 1) * CH + cbase) = pk;
    }
    if (r0 + 2 < n) {
        float d2 = dis[r0 + 2];
        pk.x = pack_bf2(a20 * d2, a21 * d2);
        pk.y = pack_bf2(a22 * d2, a23 * d2);
        pk.z = pack_bf2(a24 * d2, a25 * d2);
        pk.w = pack_bf2(a26 * d2, a27 * d2);
        *(uint4*)(Y + (size_t)(r0 + 2) * CH + cbase) = pk;
    }
    if (r0 + 3 < n) {
        float d3 = dis[r0 + 3];
        pk.x = pack_bf2(a30 * d3, a31 * d3);
        pk.y = pack_bf2(a32 * d3, a33 * d3);
        pk.z = pack_bf2(a34 * d3, a35 * d3);
        pk.w = pack_bf2(a36 * d3, a37 * d3);
        *(uint4*)(Y + (size_t)(r0 + 3) * CH + cbase) = pk;
    }
}

// R12 gather body (proven 42.2us, FETCH 88MB): 16-batches (8 loads in
// flight) + ONE-round tail (r>8 -> masked-16, else masked-8); clamped idx,
// invalid slots zeroed (exact: bf_lo(0)=0).
#define GATHER_SHFL_BODY(XWS)                                                 \
    const unsigned* XWSP = (XWS);                                             \
    int beg = rs[wid];                                                        \
    int end = rs[wid + 1];                                                    \
    unsigned cp4 = (unsigned)cp << 2;                                         \
    float accx = 0.f, accy = 0.f;                                             \
    for (int base = beg; base < end; base += 64) {                            \
        int cnt = min(64, end - base);                                        \
        int myColB = (base + lane < end) ? (col[base + lane] << 7) : 0;       \
        int eb = 0;                                                           \
        for (; eb + 16 <= cnt; eb += 16) {                                    \
            unsigned o0 = (unsigned)__shfl(myColB, eb + half, 64) | cp4;      \
            unsigned o1 = (unsigned)__shfl(myColB, eb + 2 + half, 64) | cp4;  \
            unsigned o2 = (unsigned)__shfl(myColB, eb + 4 + half, 64) | cp4;  \
            unsigned o3 = (unsigned)__shfl(myColB, eb + 6 + half, 64) | cp4;  \
            unsigned o4 = (unsigned)__shfl(myColB, eb + 8 + half, 64) | cp4;  \
            unsigned o5 = (unsigned)__shfl(myColB, eb + 10 + half, 64) | cp4; \
            unsigned o6 = (unsigned)__shfl(myColB, eb + 12 + half, 64) | cp4; \
            unsigned o7 = (unsigned)__shfl(myColB, eb + 14 + half, 64) | cp4; \
            unsigned u0 = ldu(XWSP, o0);                                      \
            unsigned u1 = ldu(XWSP, o1);                                      \
            unsigned u2 = ldu(XWSP, o2);                                      \
            unsigned u3 = ldu(XWSP, o3);                                      \
            unsigned u4 = ldu(XWSP, o4);                                      \
            unsigned u5 = ldu(XWSP, o5);                                      \
            unsigned u6 = ldu(XWSP, o6);                                      \
            unsigned u7 = ldu(XWSP, o7);                                      \
            accx += bf_lo(u0) + bf_lo(u1) + bf_lo(u2) + bf_lo(u3);            \
            accy += bf_hi(u0) + bf_hi(u1) + bf_hi(u2) + bf_hi(u3);            \
            accx += bf_lo(u4) + bf_lo(u5) + bf_lo(u6) + bf_lo(u7);            \
            accy += bf_hi(u4) + bf_hi(u5) + bf_hi(u6) + bf_hi(u7);            \
        }                                                                     \
        int r = cnt - eb;                                                     \
        int c1m = cnt - 1;                                                    \
        if (r > 8) {  /* one masked-16 round: 8 loads */                      \
            int i0 = eb + half;        int i1 = eb + 2 + half;                \
            int i2 = eb + 4 + half;    int i3 = eb + 6 + half;                \
            int i4 = eb + 8 + half;    int i5 = eb + 10 + half;               \
            int i6 = eb + 12 + half;   int i7 = eb + 14 + half;               \
            unsigned o0 = (unsigned)__shfl(myColB, min(i0, c1m), 64) | cp4;   \
            unsigned o1 = (unsigned)__shfl(myColB, min(i1, c1m), 64) | cp4;   \
            unsigned o2 = (unsigned)__shfl(myColB, min(i2, c1m), 64) | cp4;   \
            unsigned o3 = (unsigned)__shfl(myColB, min(i3, c1m), 64) | cp4;   \
            unsigned o4 = (unsigned)__shfl(myColB, min(i4, c1m), 64) | cp4;   \
            unsigned o5 = (unsigned)__shfl(myColB, min(i5, c1m), 64) | cp4;   \
            unsigned o6 = (unsigned)__shfl(myColB, min(i6, c1m), 64) | cp4;   \
            unsigned o7 = (unsigned)__shfl(myColB, min(i7, c1m), 64) | cp4;   \
            unsigned u0 = ldu(XWSP, o0);                                      \
            unsigned u1 = ldu(XWSP, o1);                                      \
            unsigned u2 = ldu(XWSP, o2);                                      \
            unsigned u3 = ldu(XWSP, o3);                                      \
            unsigned u4 = ldu(XWSP, o4);                                      \
            unsigned u5 = ldu(XWSP, o5);                                      \
            unsigned u6 = ldu(XWSP, o6);                                      \
            unsigned u7 = ldu(XWSP, o7);                                      \
            u0 = (i0 < cnt) ? u0 : 0u;  u1 = (i1 < cnt) ? u1 : 0u;            \
            u2 = (i2 < cnt) ? u2 : 0u;  u3 = (i3 < cnt) ? u3 : 0u;            \
            u4 = (i4 < cnt) ? u4 : 0u;  u5 = (i5 < cnt) ? u5 : 0u;            \
            u6 = (i6 < cnt) ? u6 : 0u;  u7 = (i7 < cnt) ? u7 : 0u;            \
            accx += bf_lo(u0) + bf_lo(u1) + bf_lo(u2) + bf_lo(u3);            \
            accy += bf_hi(u0) + bf_hi(u1) + bf_hi(u2) + bf_hi(u3);            \
            accx += bf_lo(u4) + bf_lo(u5) + bf_lo(u6) + bf_lo(u7);            \
            accy += bf_hi(u4) + bf_hi(u5) + bf_hi(u6) + bf_hi(u7);            \
        } else if (r > 0) {  /* one masked-8 round: 4 loads */                \
            int i0 = eb + half;        int i1 = eb + 2 + half;                \
            int i2 = eb + 4 + half;    int i3 = eb + 6 + half;                \
            unsigned o0 = (unsigned)__shfl(myColB, min(i0, c1m), 64) | cp4;   \
            unsigned o1 = (unsigned)__shfl(myColB, min(i1, c1m), 64) | cp4;   \
            unsigned o2 = (unsigned)__shfl(myColB, min(i2, c1m), 64) | cp4;   \
            unsigned o3 = (unsigned)__shfl(myColB, min(i3, c1m), 64) | cp4;   \
            unsigned u0 = ldu(XWSP, o0);                                      \
            unsigned u1 = ldu(XWSP, o1);                                      \
            unsigned u2 = ldu(XWSP, o2);                                      \
            unsigned u3 = ldu(XWSP, o3);                                      \
            u0 = (i0 < cnt) ? u0 : 0u;  u1 = (i1 < cnt) ? u1 : 0u;            \
            u2 = (i2 < cnt) ? u2 : 0u;  u3 = (i3 < cnt) ? u3 : 0u;            \
            accx += bf_lo(u0) + bf_lo(u1) + bf_lo(u2) + bf_lo(u3);            \
            accy += bf_hi(u0) + bf_hi(u1) + bf_hi(u2) + bf_hi(u3);            \
        }                                                                     \
    }                                                                         \
    accx += __shfl_xor(accx, 32, 64);                                         \
    accy += __shfl_xor(accy, 32, 64);

// Layer-1 gather: h[wid, 2cp]=vx, h[wid, 2cp+1]=vy (fp32, dense float2/lane).
// One node per wave (max TLP).  Self-term us/dd/bias hoisted (R5, proven).
__global__ __launch_bounds__(256)
void gather_pair_kernel(const unsigned* __restrict__ xws, const int* __restrict__ col,
                        const int* __restrict__ rs, const float* __restrict__ dis,
                        const float* __restrict__ b1, float* __restrict__ h,
                        int n, int E) {
    int wid = blockIdx.x * 4 + (threadIdx.x >> 6);
    int lane = threadIdx.x & 63;
    int cp = lane & 31;
    int half = lane >> 5;
    if (wid >= n) return;

    unsigned us = xws[(size_t)wid * 32 + cp];   // hoisted: overlaps gather
    float dd = dis[wid];
    float2 bb = ((const float2*)b1)[cp];

    GATHER_SHFL_BODY(xws)

    if (half == 0) {
        float2 o;
        o.x = fmaxf(dd * (accx + bf_lo(us)) + bb.x, 0.f);
        o.y = fmaxf(dd * (accy + bf_hi(us)) + bb.y, 0.f);
        ((float2*)h)[(size_t)wid * 32 + cp] = o;  // 8B/lane, dense 256B
    }
}

// Layer-2 gather + relu + per-block LN partials (NON-atomic per-block stores
// — R1/R2 lesson).
__global__ __launch_bounds__(256)
void gather_stats_kernel(const unsigned* __restrict__ xws, const int* __restrict__ col,
                         const int* __restrict__ rs, const float* __restrict__ dis,
                         const float* __restrict__ b2, float* __restrict__ out,
                         int n, int E, float* __restrict__ sums, float* __restrict__ sqs) {
    int wid = blockIdx.x * 4 + (threadIdx.x >> 6);
    int lane = threadIdx.x & 63;
    int cp = lane & 31;
    int half = lane >> 5;
    float vx = 0.f, vy = 0.f;
    if (wid < n) {
        unsigned us = xws[(size_t)wid * 32 + cp];   // hoisted
        float dd = dis[wid];
        float2 bb = ((const float2*)b2)[cp];
        GATHER_SHFL_BODY(xws)
        vx = fmaxf(dd * (accx + bf_lo(us)) + bb.x, 0.f);
        vy = fmaxf(dd * (accy + bf_hi(us)) + bb.y, 0.f);
        if (half == 0) {
            float2 o; o.x = vx; o.y = vy;
            ((float2*)out)[(size_t)wid * 32 + cp] = o;
        }
    }
    float s = (half == 0) ? vx + vy : 0.f;
    float sq = (half == 0) ? vx * vx + vy * vy : 0.f;
#pragma unroll
    for (int off = 32; off > 0; off >>= 1) {
        s += __shfl_down(s, off, 64);
        sq += __shfl_down(sq, off, 64);
    }
    __shared__ float ls[4], lq[4];
    int w = threadIdx.x >> 6;
    if ((threadIdx.x & 63) == 0) { ls[w] = s; lq[w] = sq; }
    __syncthreads();
    if (threadIdx.x == 0) {
        sums[blockIdx.x] = ls[0] + ls[1] + ls[2] + ls[3];
        sqs[blockIdx.x] = lq[0] + lq[1] + lq[2] + lq[3];
    }
}

// R13: reduce_final + norm fused into ONE cooperative kernel (3 phases).
// 512 blocks x 256 thr -> 2 blocks/CU co-residency, trivially satisfied.
__global__ __launch_bounds__(256)
void norm_coop_kernel(const float* __restrict__ sums, const float* __restrict__ sqs,
                      int nparts, float n_total, const float* __restrict__ lnw,
                      const float* __restrict__ lnb, float* __restrict__ so,
                      float* __restrict__ gsum, float* __restrict__ gsq,
                      float* __restrict__ x, int n8) {
    cg::grid_group grid = cg::this_grid();
    __shared__ float ls[4], lq[4];
    int t = threadIdx.x;
    int gid = blockIdx.x * 256 + t;
    int gstride = gridDim.x * 256;
    // phase 1: per-block partial of partials
    float s = 0.f, q = 0.f;
    for (int i = gid; i < nparts; i += gstride) { s += sums[i]; q += sqs[i]; }
#pragma unroll
    for (int off = 32; off > 0; off >>= 1) {
        s += __shfl_down(s, off, 64);
        q += __shfl_down(q, off, 64);
    }
    int w = t >> 6;
    if ((t & 63) == 0) { ls[w] = s; lq[w] = q; }
    __syncthreads();
    if (t == 0) {
        gsum[blockIdx.x] = ls[0] + ls[1] + ls[2] + ls[3];
        gsq[blockIdx.x]  = lq[0] + lq[1] + lq[2] + lq[3];
    }
    grid.sync();
    // phase 2: block 0 folds gridDim partials -> scale/offset
    if (blockIdx.x == 0) {
        float s2 = 0.f, q2 = 0.f;
        for (int i = t; i < (int)gridDim.x; i += 256) { s2 += gsum[i]; q2 += gsq[i]; }
#pragma unroll
        for (int off = 32; off > 0; off >>= 1) {
            s2 += __shfl_down(s2, off, 64);
            q2 += __shfl_down(q2, off, 64);
        }
        __syncthreads();
        if ((t & 63) == 0) { ls[t >> 6] = s2; lq[t >> 6] = q2; }
        __syncthreads();
        if (t == 0) {
            float ts = ls[0] + ls[1] + ls[2] + ls[3];
            float tq = lq[0] + lq[1] + lq[2] + lq[3];
            float mean = ts / n_total;
            float var = tq / n_total - mean * mean;
            float scale = rsqrtf(var + 1e-5f) * lnw[0];
            so[0] = scale;
            so[1] = lnb[0] - mean * scale;
        }
    }
    grid.sync();
    // phase 3: grid-stride normalize (32B/thread/iter)
    float scale = so[0], off = so[1];
    float4* x4 = (float4*)x;
    for (int i = gid; i < n8; i += gstride) {
        float4 a = x4[2 * i];
        float4 b = x4[2 * i + 1];
        a.x = a.x * scale + off; a.y = a.y * scale + off;
        a.z = a.z * scale + off; a.w = a.w * scale + off;
        b.x = b.x * scale + off; b.y = b.y * scale + off;
        b.z = b.z * scale + off; b.w = b.w * scale + off;
        x4[2 * i] = a;
        x4[2 * i + 1] = b;
    }
}

extern "C" void kernel_launch(void* const* d_in, const int* in_sizes, int n_in,
                              void* d_out, int out_size, void* d_ws, size_t ws_size,
                              hipStream_t stream) {
    const float* X   = (const float*)d_in[0];
    const int*   edg = (const int*)d_in[1];   // [2,E]: src row then dst row
    const float* W1  = (const float*)d_in[2];
    const float* b1  = (const float*)d_in[3];
    const float* W2  = (const float*)d_in[4];
    const float* b2  = (const float*)d_in[5];
    const float* lnw = (const float*)d_in[6];
    const float* lnb = (const float*)d_in[7];
    float* out = (float*)d_out;

    const int N  = in_sizes[0] / CH;   // 100000
    const int E  = in_sizes[1] / 2;    // 1600000
    const int NC = N * CH;             // 6.4M
    const int nNodeBlk = (N + 3) / 4;  // 25000 (4 nodes / block)
    const int nb = (N + 511) >> BSH;   // 196 buckets
    const int nblkE = (E + CHUNK - 1) / CHUNK;  // 98 edge-chunk blocks
    const int nvblk = nblkE * NREP;    // 392 virtual hist blocks

    const int* srcp = edg;
    const int* dstp = edg + E;

    // workspace layout (4B units).  ALIGNMENT RULE (R12): rs padded to N+32
    // so dis/xws1/xws2/h stay 128B-aligned.
    int*   col   = (int*)d_ws;                          // E (aligned)
    int*   rs    = col + E;                             // N+1 used, N+32 reserved
    float* dis   = (float*)(rs + N + 32);               // N (aligned)
    __hip_bfloat16* xws1 = (__hip_bfloat16*)(dis + N);  // NC bf16 (128B rows)
    __hip_bfloat16* xws2 = xws1 + NC;                   // NC bf16 (128B rows)
    float* h     = (float*)(xws2 + NC);                 // NC floats (256B rows)
    unsigned* pairs = (unsigned*)h;                     // E u32 (dead before h live)
    int*   bHist = (int*)(h + NC);                      // nvblk*nb
    int*   bStart= bHist + nvblk * nb;                  // nb+1
    float* sums  = (float*)(bStart + nb + 1);           // nNodeBlk
    float* sqs   = sums + nNodeBlk;                     // nNodeBlk
    float* so    = sqs + nNodeBlk;                      // 2 {scale, offset}
    float* gsum  = so + 2;                              // 512
    float* gsq   = gsum + 512;                          // 512

    const int B = 256;
    const int nGemmBlk = (N + 127) / 128;               // 782 (4 rows/thread)

    // ---- CSR build: ONE cooperative kernel (4 grid-synced phases) ----
    {
        int Nv = N, nbv = nb, Ev = E, nblkEv = nblkE;
        void* cargs[] = {(void*)&srcp, (void*)&dstp, (void*)&bHist, (void*)&bStart,
                         (void*)&pairs, (void*)&col, (void*)&rs, (void*)&dis,
                         (void*)&Nv, (void*)&nbv, (void*)&Ev, (void*)&nblkEv};
        hipLaunchCooperativeKernel((const void*)csr_coop_kernel, dim3(nb), dim3(1024),
                                   cargs, 0, stream);
    }

    // ---- layer 1 ----
    gemm64_scaled_kernel<<<nGemmBlk, B, 0, stream>>>(X, W1, dis, xws1, N);
    gather_pair_kernel<<<nNodeBlk, B, 0, stream>>>((const unsigned*)xws1, col, rs, dis,
                                                   b1, h, N, E);

    // ---- layer 2 ----
    gemm64_scaled_kernel<<<nGemmBlk, B, 0, stream>>>(h, W2, dis, xws2, N);
    gather_stats_kernel<<<nNodeBlk, B, 0, stream>>>((const unsigned*)xws2, col, rs, dis,
                                                    b2, out, N, E, sums, sqs);

    // ---- graph layernorm: ONE cooperative kernel (reduce + norm) ----
    {
        int npart = nNodeBlk;
        float ntot = (float)NC;
        int n8 = NC / 8;
        void* nargs[] = {(void*)&sums, (void*)&sqs, (void*)&npart, (void*)&ntot,
                         (void*)&lnw, (void*)&lnb, (void*)&so, (void*)&gsum,
                         (void*)&gsq, (void*)&out, (void*)&n8};
        hipLaunchCooperativeKernel((const void*)norm_coop_kernel, dim3(512), dim3(256),
                                   nargs, 0, stream);
    }
}

// Round 14
// 252.177 us; speedup vs baseline: 1.7340x; 1.7340x over previous
//
#include <hip/hip_runtime.h>
#include <hip/hip_bf16.h>

#define CH 64          // IN_C = HID_C = OUT_C = 64
#define BSH 9          // bucket shift: 512 nodes/bucket
#define CHUNK 16384    // edges per block in scatter pass (1024 thr x 16)
#define MAXB 10240     // LDS col buffer (edges/bucket ~8163 +- 90)
#define MAXCAP 16384   // fixed pairs region per bucket (>= 8163 + huge slack)
#define NREP 4         // LDS histogram replicas (quarter-block each)
#define RPAD 257       // replica stride: 257 ints rotates bank mapping
// pairs packing: src < 2^17 (N=100000 <= 131072), dstLocal < 2^9 -> 26 bits
//
// SESSION LEDGER (hard-won):
//  R1/R2: 25k global atomicAdds to ONE cache line serialize cross-XCD = +276us.
//  R4:    in-wave GEMM via shfl+LDS: DS-pipe chains poison gather epilogues.
//  R7:    serial load-rounds are the gather lever at constant load count.
//  R10-12: FETCH tracks cache-LINE touches; ALIGNMENT RULE: any workspace
//         change must re-verify 128B alignment of row-granular buffers.
//  R13:   cooperative kernels BANNED here: grid.sync = 196 blocks polling one
//         device-scope line (csr_coop 105us, VALU 1.6%), and coop LAUNCHES
//         cost ~100us extra.  BUT the audit stands: ~8.5us per regular
//         launch x 10 = ~85us overhead in R12.  Lever: fewer REGULAR kernels.
//  R14:   this round — CSR 4 -> 3 regular kernels via fixed-capacity bucket
//         regions: zero_cnt(tiny) + scatter_direct (count + 1 line-padded
//         chunk-grab atomic per (block,bucket) + scatter) + bucket_direct
//         (per-block 196-scan for start; else R12 bucket verbatim).  Deletes
//         scan_hist + separate hist pass + blockHist traffic.
//  prev:  scalar s_load of col regressed; serial nodes/wave regressed 2.3x.

// ---------- CSR build: 3 regular kernels ----------

__global__ __launch_bounds__(1024)
void zero_cnt_kernel(int* __restrict__ p, int n) {
    int i = blockIdx.x * 1024 + threadIdx.x;
    if (i < n) p[i] = 0;
}

// Pass A: 4-replica LDS hist of this block's 16k edges.  Chunk-grab: thread
// t<nb sums replicas for bucket t, ONE global atomicAdd on line-padded
// bucketCnt[t*16] (98 atomics/counter, lines parallel).  Cursors = absolute
// pairs indices (bucket*MAXCAP + off + replica prefix).  Pass B: scatter
// (identical structure to R12's proven scatter).
__global__ __launch_bounds__(1024)
void scatter_direct_kernel(const int* __restrict__ src, const int* __restrict__ dst,
                           int* __restrict__ bucketCnt, unsigned* __restrict__ pairs,
                           int E, int nb) {
    __shared__ int h[NREP * RPAD];
    int t = threadIdx.x;
    int rep = t >> 8;
    for (int i = t; i < NREP * RPAD; i += 1024) h[i] = 0;
    __syncthreads();
    int* hr = h + rep * RPAD;
    int base = blockIdx.x * CHUNK + t * 16;
#pragma unroll
    for (int j = 0; j < 16; j += 4) {      // pass A: count
        int e = base + j;
        if (e + 3 < E) {
            int4 d = *(const int4*)(dst + e);
            atomicAdd(&hr[d.x >> BSH], 1);
            atomicAdd(&hr[d.y >> BSH], 1);
            atomicAdd(&hr[d.z >> BSH], 1);
            atomicAdd(&hr[d.w >> BSH], 1);
        } else {
            for (int k = e; k < E && k < e + 4; ++k) atomicAdd(&hr[dst[k] >> BSH], 1);
        }
    }
    __syncthreads();
    if (t < nb) {                          // chunk grab, bucket t
        int c0 = h[0 * RPAD + t];
        int c1 = h[1 * RPAD + t];
        int c2 = h[2 * RPAD + t];
        int c3 = h[3 * RPAD + t];
        int tot = c0 + c1 + c2 + c3;
        int off = (tot > 0) ? atomicAdd(&bucketCnt[t * 16], tot) : 0;
        int abs0 = t * MAXCAP + off;       // absolute pairs index
        h[0 * RPAD + t] = abs0;
        h[1 * RPAD + t] = abs0 + c0;
        h[2 * RPAD + t] = abs0 + c0 + c1;
        h[3 * RPAD + t] = abs0 + c0 + c1 + c2;
    }
    __syncthreads();
    int* cr = h + rep * RPAD;
#pragma unroll
    for (int j = 0; j < 16; j += 4) {      // pass B: scatter
        int e = base + j;
        if (e + 3 < E) {
            int4 d = *(const int4*)(dst + e);
            int4 s = *(const int4*)(src + e);
            int p0 = atomicAdd(&cr[d.x >> BSH], 1);
            pairs[p0] = ((unsigned)(d.x & 511) << 17) | (unsigned)s.x;
            int p1 = atomicAdd(&cr[d.y >> BSH], 1);
            pairs[p1] = ((unsigned)(d.y & 511) << 17) | (unsigned)s.y;
            int p2 = atomicAdd(&cr[d.z >> BSH], 1);
            pairs[p2] = ((unsigned)(d.z & 511) << 17) | (unsigned)s.z;
            int p3 = atomicAdd(&cr[d.w >> BSH], 1);
            pairs[p3] = ((unsigned)(d.w & 511) << 17) | (unsigned)s.w;
        } else {
            for (int k = e; k < E && k < e + 4; ++k) {
                int d = dst[k];
                int p = atomicAdd(&cr[d >> BSH], 1);
                pairs[p] = ((unsigned)(d & 511) << 17) | (unsigned)src[k];
            }
        }
    }
}

// Per-block: load 196 final counts, 256-wide LDS exclusive scan -> start
// (replaces scan_hist).  Rest = R12 bucket kernel verbatim, reading the
// bucket's fixed region pairs[b*MAXCAP ..].
__global__ __launch_bounds__(1024)
void bucket_direct_kernel(const unsigned* __restrict__ pairs, const int* __restrict__ bucketCnt,
                          int* __restrict__ col, int* __restrict__ rs, float* __restrict__ dis,
                          int N, int nb, int E) {
    __shared__ int hist[512];
    __shared__ int offs[512];
    __shared__ int cursor[512];
    __shared__ int lcol[MAXB];
    __shared__ int bcnt[256];
    __shared__ int bscan[256];
    int b = blockIdx.x;
    int t = threadIdx.x;
    if (t < 256) {
        int c = (t < nb) ? bucketCnt[t * 16] : 0;
        bcnt[t] = c;
        bscan[t] = c;
    }
    __syncthreads();
    for (int off = 1; off < 256; off <<= 1) {
        int a = (t < 256 && t >= off) ? bscan[t - off] : 0;
        __syncthreads();
        if (t < 256) bscan[t] += a;
        __syncthreads();
    }
    int cnt = bcnt[b];
    int start = bscan[b] - cnt;            // exclusive prefix = final col offset
    const unsigned* mypairs = pairs + (size_t)b * MAXCAP;
    int n0 = b << BSH;
    int nn = min(512, N - n0);
    bool big = cnt > MAXB;  // safety fallback: direct (uncoalesced) col writes
    for (int i = t; i < nn; i += 1024) hist[i] = 0;
    __syncthreads();
    for (int i = t; i < cnt; i += 1024) {
        unsigned p = mypairs[i];
        atomicAdd(&hist[p >> 17], 1);
    }
    __syncthreads();
    if (t < 512) offs[t] = (t < nn) ? hist[t] : 0;
    __syncthreads();
    for (int off = 1; off < 512; off <<= 1) {
        int a = (t < 512 && t >= off) ? offs[t - off] : 0;
        __syncthreads();
        if (t < 512) offs[t] += a;
        __syncthreads();
    }
    if (t < nn) {
        int excl = offs[t] - hist[t];          // exclusive scan value
        rs[n0 + t] = start + excl;
        dis[n0 + t] = rsqrtf((float)hist[t] + 1.0f);
        cursor[t] = excl;
    }
    if (b == 0 && t == 0) rs[N] = E;           // branchless gather end
    __syncthreads();
    for (int i = t; i < cnt; i += 1024) {
        unsigned p = mypairs[i];
        int pos = atomicAdd(&cursor[p >> 17], 1);
        int sv = (int)(p & 0x1FFFFu);
        if (big) col[start + pos] = sv;
        else lcol[pos] = sv;
    }
    __syncthreads();
    if (!big) {
        for (int i = t; i < cnt; i += 1024) col[start + i] = lcol[i];
    }
}

// ---------- compute ----------

__device__ inline unsigned pack_bf2(float a, float b) {
    __hip_bfloat162 t;
    t.x = __float2bfloat16(a);
    t.y = __float2bfloat16(b);
    unsigned u;
    __builtin_memcpy(&u, &t, 4);
    return u;
}

__device__ inline float bf_lo(unsigned u) {
    unsigned w = u << 16; float f; __builtin_memcpy(&f, &w, 4); return f;
}
__device__ inline float bf_hi(unsigned u) {
    unsigned w = u & 0xffff0000u; float f; __builtin_memcpy(&f, &w, 4); return f;
}

// uniform-base + 32-bit byte-offset load -> global_load_dword v, voff, s[base]
__device__ inline unsigned ldu(const unsigned* p, unsigned boff) {
    return *(const unsigned*)((const char*)p + boff);
}

#define FMA32(x0, x1, x2, x3, wa, wb)                                        \
    a00 += (x0) * (wa).x; a01 += (x0) * (wa).y;                              \
    a02 += (x0) * (wa).z; a03 += (x0) * (wa).w;                              \
    a04 += (x0) * (wb).x; a05 += (x0) * (wb).y;                              \
    a06 += (x0) * (wb).z; a07 += (x0) * (wb).w;                              \
    a10 += (x1) * (wa).x; a11 += (x1) * (wa).y;                              \
    a12 += (x1) * (wa).z; a13 += (x1) * (wa).w;                              \
    a14 += (x1) * (wb).x; a15 += (x1) * (wb).y;                              \
    a16 += (x1) * (wb).z; a17 += (x1) * (wb).w;                              \
    a20 += (x2) * (wa).x; a21 += (x2) * (wa).y;                              \
    a22 += (x2) * (wa).z; a23 += (x2) * (wa).w;                              \
    a24 += (x2) * (wb).x; a25 += (x2) * (wb).y;                              \
    a26 += (x2) * (wb).z; a27 += (x2) * (wb).w;                              \
    a30 += (x3) * (wa).x; a31 += (x3) * (wa).y;                              \
    a32 += (x3) * (wa).z; a33 += (x3) * (wa).w;                              \
    a34 += (x3) * (wb).x; a35 += (x3) * (wb).y;                              \
    a36 += (x3) * (wb).z; a37 += (x3) * (wb).w;

// GEMM: 4 rows x 8 cols per thread (R1-R12: correctness-proven).  All named
// scalars.  unroll 2 under the 128-VGPR cap of (256,4).
__global__ __launch_bounds__(256, 4)
void gemm64_scaled_kernel(const float* __restrict__ X, const float* __restrict__ W,
                          const float* __restrict__ dis,
                          __hip_bfloat16* __restrict__ Y, int n) {
    __shared__ float Ws[CH * CH];
    {
        float4* w4 = (float4*)Ws;
        const float4* g4 = (const float4*)W;
        for (int i = threadIdx.x; i < CH * CH / 4; i += 256) w4[i] = g4[i];
    }
    __syncthreads();
    int t = threadIdx.x;
    int cbase = (t & 7) * 8;
    int r0 = blockIdx.x * 128 + (t >> 3) * 4;
    if (r0 >= n) return;
    int rB = min(r0 + 1, n - 1);
    int rC = min(r0 + 2, n - 1);
    int rD = min(r0 + 3, n - 1);
    const float4* pA = (const float4*)(X + (size_t)r0 * CH);
    const float4* pB = (const float4*)(X + (size_t)rB * CH);
    const float4* pC = (const float4*)(X + (size_t)rC * CH);
    const float4* pD = (const float4*)(X + (size_t)rD * CH);

    float a00 = 0.f, a01 = 0.f, a02 = 0.f, a03 = 0.f;
    float a04 = 0.f, a05 = 0.f, a06 = 0.f, a07 = 0.f;
    float a10 = 0.f, a11 = 0.f, a12 = 0.f, a13 = 0.f;
    float a14 = 0.f, a15 = 0.f, a16 = 0.f, a17 = 0.f;
    float a20 = 0.f, a21 = 0.f, a22 = 0.f, a23 = 0.f;
    float a24 = 0.f, a25 = 0.f, a26 = 0.f, a27 = 0.f;
    float a30 = 0.f, a31 = 0.f, a32 = 0.f, a33 = 0.f;
    float a34 = 0.f, a35 = 0.f, a36 = 0.f, a37 = 0.f;

#pragma unroll 2
    for (int k4 = 0; k4 < CH / 4; ++k4) {
        float4 xa = pA[k4];
        float4 xb = pB[k4];
        float4 xc = pC[k4];
        float4 xd = pD[k4];
        const float* wr = &Ws[(k4 * 4) * CH + cbase];
        float4 wa, wb;
        wa = *(const float4*)(wr);
        wb = *(const float4*)(wr + 4);
        FMA32(xa.x, xb.x, xc.x, xd.x, wa, wb)
        wa = *(const float4*)(wr + CH);
        wb = *(const float4*)(wr + CH + 4);
        FMA32(xa.y, xb.y, xc.y, xd.y, wa, wb)
        wa = *(const float4*)(wr + 2 * CH);
        wb = *(const float4*)(wr + 2 * CH + 4);
        FMA32(xa.z, xb.z, xc.z, xd.z, wa, wb)
        wa = *(const float4*)(wr + 3 * CH);
        wb = *(const float4*)(wr + 3 * CH + 4);
        FMA32(xa.w, xb.w, xc.w, xd.w, wa, wb)
    }

    uint4 pk;
    float d0 = dis[r0];
    pk.x = pack_bf2(a00 * d0, a01 * d0);
    pk.y = pack_bf2(a02 * d0, a03 * d0);
    pk.z = pack_bf2(a04 * d0, a05 * d0);
    pk.w = pack_bf2(a06 * d0, a07 * d0);
    *(uint4*)(Y + (size_t)r0 * CH + cbase) = pk;
    if (r0 + 1 < n) {
        float d1 = dis[r0 + 1];
        pk.x = pack_bf2(a10 * d1, a11 * d1);
        pk.y = pack_bf2(a12 * d1, a13 * d1);
        pk.z = pack_bf2(a14 * d1, a15 * d1);
        pk.w = pack_bf2(a16 * d1, a17 * d1);
        *(uint4*)(Y + (size_t)(r0 + 1) * CH + cbase) = pk;
    }
    if (r0 + 2 < n) {
        float d2 = dis[r0 + 2];
        pk.x = pack_bf2(a20 * d2, a21 * d2);
        pk.y = pack_bf2(a22 * d2, a23 * d2);
        pk.z = pack_bf2(a24 * d2, a25 * d2);
        pk.w = pack_bf2(a26 * d2, a27 * d2);
        *(uint4*)(Y + (size_t)(r0 + 2) * CH + cbase) = pk;
    }
    if (r0 + 3 < n) {
        float d3 = dis[r0 + 3];
        pk.x = pack_bf2(a30 * d3, a31 * d3);
        pk.y = pack_bf2(a32 * d3, a33 * d3);
        pk.z = pack_bf2(a34 * d3, a35 * d3);
        pk.w = pack_bf2(a36 * d3, a37 * d3);
        *(uint4*)(Y + (size_t)(r0 + 3) * CH + cbase) = pk;
    }
}

// R12 gather body (proven 42.2us, FETCH 88MB): 16-batches (8 loads in
// flight) + ONE-round tail (r>8 -> masked-16, else masked-8); clamped idx,
// invalid slots zeroed (exact: bf_lo(0)=0).
#define GATHER_SHFL_BODY(XWS)                                                 \
    const unsigned* XWSP = (XWS);                                             \
    int beg = rs[wid];                                                        \
    int end = rs[wid + 1];                                                    \
    unsigned cp4 = (unsigned)cp << 2;                                         \
    float accx = 0.f, accy = 0.f;                                             \
    for (int base = beg; base < end; base += 64) {                            \
        int cnt = min(64, end - base);                                        \
        int myColB = (base + lane < end) ? (col[base + lane] << 7) : 0;       \
        int eb = 0;                                                           \
        for (; eb + 16 <= cnt; eb += 16) {                                    \
            unsigned o0 = (unsigned)__shfl(myColB, eb + half, 64) | cp4;      \
            unsigned o1 = (unsigned)__shfl(myColB, eb + 2 + half, 64) | cp4;  \
            unsigned o2 = (unsigned)__shfl(myColB, eb + 4 + half, 64) | cp4;  \
            unsigned o3 = (unsigned)__shfl(myColB, eb + 6 + half, 64) | cp4;  \
            unsigned o4 = (unsigned)__shfl(myColB, eb + 8 + half, 64) | cp4;  \
            unsigned o5 = (unsigned)__shfl(myColB, eb + 10 + half, 64) | cp4; \
            unsigned o6 = (unsigned)__shfl(myColB, eb + 12 + half, 64) | cp4; \
            unsigned o7 = (unsigned)__shfl(myColB, eb + 14 + half, 64) | cp4; \
            unsigned u0 = ldu(XWSP, o0);                                      \
            unsigned u1 = ldu(XWSP, o1);                                      \
            unsigned u2 = ldu(XWSP, o2);                                      \
            unsigned u3 = ldu(XWSP, o3);                                      \
            unsigned u4 = ldu(XWSP, o4);                                      \
            unsigned u5 = ldu(XWSP, o5);                                      \
            unsigned u6 = ldu(XWSP, o6);                                      \
            unsigned u7 = ldu(XWSP, o7);                                      \
            accx += bf_lo(u0) + bf_lo(u1) + bf_lo(u2) + bf_lo(u3);            \
            accy += bf_hi(u0) + bf_hi(u1) + bf_hi(u2) + bf_hi(u3);            \
            accx += bf_lo(u4) + bf_lo(u5) + bf_lo(u6) + bf_lo(u7);            \
            accy += bf_hi(u4) + bf_hi(u5) + bf_hi(u6) + bf_hi(u7);            \
        }                                                                     \
        int r = cnt - eb;                                                     \
        int c1m = cnt - 1;                                                    \
        if (r > 8) {  /* one masked-16 round: 8 loads */                      \
            int i0 = eb + half;        int i1 = eb + 2 + half;                \
            int i2 = eb + 4 + half;    int i3 = eb + 6 + half;                \
            int i4 = eb + 8 + half;    int i5 = eb + 10 + half;               \
            int i6 = eb + 12 + half;   int i7 = eb + 14 + half;               \
            unsigned o0 = (unsigned)__shfl(myColB, min(i0, c1m), 64) | cp4;   \
            unsigned o1 = (unsigned)__shfl(myColB, min(i1, c1m), 64) | cp4;   \
            unsigned o2 = (unsigned)__shfl(myColB, min(i2, c1m), 64) | cp4;   \
            unsigned o3 = (unsigned)__shfl(myColB, min(i3, c1m), 64) | cp4;   \
            unsigned o4 = (unsigned)__shfl(myColB, min(i4, c1m), 64) | cp4;   \
            unsigned o5 = (unsigned)__shfl(myColB, min(i5, c1m), 64) | cp4;   \
            unsigned o6 = (unsigned)__shfl(myColB, min(i6, c1m), 64) | cp4;   \
            unsigned o7 = (unsigned)__shfl(myColB, min(i7, c1m), 64) | cp4;   \
            unsigned u0 = ldu(XWSP, o0);                                      \
            unsigned u1 = ldu(XWSP, o1);                                      \
            unsigned u2 = ldu(XWSP, o2);                                      \
            unsigned u3 = ldu(XWSP, o3);                                      \
            unsigned u4 = ldu(XWSP, o4);                                      \
            unsigned u5 = ldu(XWSP, o5);                                      \
            unsigned u6 = ldu(XWSP, o6);                                      \
            unsigned u7 = ldu(XWSP, o7);                                      \
            u0 = (i0 < cnt) ? u0 : 0u;  u1 = (i1 < cnt) ? u1 : 0u;            \
            u2 = (i2 < cnt) ? u2 : 0u;  u3 = (i3 < cnt) ? u3 : 0u;            \
            u4 = (i4 < cnt) ? u4 : 0u;  u5 = (i5 < cnt) ? u5 : 0u;            \
            u6 = (i6 < cnt) ? u6 : 0u;  u7 = (i7 < cnt) ? u7 : 0u;            \
            accx += bf_lo(u0) + bf_lo(u1) + bf_lo(u2) + bf_lo(u3);            \
            accy += bf_hi(u0) + bf_hi(u1) + bf_hi(u2) + bf_hi(u3);            \
            accx += bf_lo(u4) + bf_lo(u5) + bf_lo(u6) + bf_lo(u7);            \
            accy += bf_hi(u4) + bf_hi(u5) + bf_hi(u6) + bf_hi(u7);            \
        } else if (r > 0) {  /* one masked-8 round: 4 loads */                \
            int i0 = eb + half;        int i1 = eb + 2 + half;                \
            int i2 = eb + 4 + half;    int i3 = eb + 6 + half;                \
            unsigned o0 = (unsigned)__shfl(myColB, min(i0, c1m), 64) | cp4;   \
            unsigned o1 = (unsigned)__shfl(myColB, min(i1, c1m), 64) | cp4;   \
            unsigned o2 = (unsigned)__shfl(myColB, min(i2, c1m), 64) | cp4;   \
            unsigned o3 = (unsigned)__shfl(myColB, min(i3, c1m), 64) | cp4;   \
            unsigned u0 = ldu(XWSP, o0);                                      \
            unsigned u1 = ldu(XWSP, o1);                                      \
            unsigned u2 = ldu(XWSP, o2);                                      \
            unsigned u3 = ldu(XWSP, o3);                                      \
            u0 = (i0 < cnt) ? u0 : 0u;  u1 = (i1 < cnt) ? u1 : 0u;            \
            u2 = (i2 < cnt) ? u2 : 0u;  u3 = (i3 < cnt) ? u3 : 0u;            \
            accx += bf_lo(u0) + bf_lo(u1) + bf_lo(u2) + bf_lo(u3);            \
            accy += bf_hi(u0) + bf_hi(u1) + bf_hi(u2) + bf_hi(u3);            \
        }                                                                     \
    }                                                                         \
    accx += __shfl_xor(accx, 32, 64);                                         \
    accy += __shfl_xor(accy, 32, 64);

// Layer-1 gather: h[wid, 2cp]=vx, h[wid, 2cp+1]=vy (fp32, dense float2/lane).
// One node per wave (max TLP).  Self-term us/dd/bias hoisted (R5, proven).
__global__ __launch_bounds__(256)
void gather_pair_kernel(const unsigned* __restrict__ xws, const int* __restrict__ col,
                        const int* __restrict__ rs, const float* __restrict__ dis,
                        const float* __restrict__ b1, float* __restrict__ h,
                        int n, int E) {
    int wid = blockIdx.x * 4 + (threadIdx.x >> 6);
    int lane = threadIdx.x & 63;
    int cp = lane & 31;
    int half = lane >> 5;
    if (wid >= n) return;

    unsigned us = xws[(size_t)wid * 32 + cp];   // hoisted: overlaps gather
    float dd = dis[wid];
    float2 bb = ((const float2*)b1)[cp];

    GATHER_SHFL_BODY(xws)

    if (half == 0) {
        float2 o;
        o.x = fmaxf(dd * (accx + bf_lo(us)) + bb.x, 0.f);
        o.y = fmaxf(dd * (accy + bf_hi(us)) + bb.y, 0.f);
        ((float2*)h)[(size_t)wid * 32 + cp] = o;  // 8B/lane, dense 256B
    }
}

// Layer-2 gather + relu + per-block LN partials (NON-atomic per-block stores
// — R1/R2 lesson).
__global__ __launch_bounds__(256)
void gather_stats_kernel(const unsigned* __restrict__ xws, const int* __restrict__ col,
                         const int* __restrict__ rs, const float* __restrict__ dis,
                         const float* __restrict__ b2, float* __restrict__ out,
                         int n, int E, float* __restrict__ sums, float* __restrict__ sqs) {
    int wid = blockIdx.x * 4 + (threadIdx.x >> 6);
    int lane = threadIdx.x & 63;
    int cp = lane & 31;
    int half = lane >> 5;
    float vx = 0.f, vy = 0.f;
    if (wid < n) {
        unsigned us = xws[(size_t)wid * 32 + cp];   // hoisted
        float dd = dis[wid];
        float2 bb = ((const float2*)b2)[cp];
        GATHER_SHFL_BODY(xws)
        vx = fmaxf(dd * (accx + bf_lo(us)) + bb.x, 0.f);
        vy = fmaxf(dd * (accy + bf_hi(us)) + bb.y, 0.f);
        if (half == 0) {
            float2 o; o.x = vx; o.y = vy;
            ((float2*)out)[(size_t)wid * 32 + cp] = o;
        }
    }
    float s = (half == 0) ? vx + vy : 0.f;
    float sq = (half == 0) ? vx * vx + vy * vy : 0.f;
#pragma unroll
    for (int off = 32; off > 0; off >>= 1) {
        s += __shfl_down(s, off, 64);
        sq += __shfl_down(sq, off, 64);
    }
    __shared__ float ls[4], lq[4];
    int w = threadIdx.x >> 6;
    if ((threadIdx.x & 63) == 0) { ls[w] = s; lq[w] = sq; }
    __syncthreads();
    if (threadIdx.x == 0) {
        sums[blockIdx.x] = ls[0] + ls[1] + ls[2] + ls[3];
        sqs[blockIdx.x] = lq[0] + lq[1] + lq[2] + lq[3];
    }
}

__global__ void reduce_final_kernel(const float* __restrict__ sums, const float* __restrict__ sqs,
                                    int nb, float n_total, const float* __restrict__ lnw,
                                    const float* __restrict__ lnb, float* __restrict__ so) {
    float s = 0.0f, sq = 0.0f;
    for (int i = threadIdx.x; i < nb; i += 1024) { s += sums[i]; sq += sqs[i]; }
#pragma unroll
    for (int off = 32; off > 0; off >>= 1) {
        s += __shfl_down(s, off, 64);
        sq += __shfl_down(sq, off, 64);
    }
    __shared__ float ls[16], lq[16];
    int w = threadIdx.x >> 6;
    if ((threadIdx.x & 63) == 0) { ls[w] = s; lq[w] = sq; }
    __syncthreads();
    if (threadIdx.x == 0) {
        float ts = 0.0f, tq = 0.0f;
        for (int i = 0; i < 16; ++i) { ts += ls[i]; tq += lq[i]; }
        float mean = ts / n_total;
        float var = tq / n_total - mean * mean;
        float scale = rsqrtf(var + 1e-5f) * lnw[0];
        so[0] = scale;
        so[1] = lnb[0] - mean * scale;
    }
}

// 32B/thread (2x float4): halves block count vs 16B/thread.
__global__ void norm_kernel(float* __restrict__ x, int n8, const float* __restrict__ so) {
    int i = blockIdx.x * blockDim.x + threadIdx.x;
    if (i >= n8) return;
    float scale = so[0], off = so[1];
    float4* x4 = (float4*)x;
    float4 a = x4[2 * i];
    float4 b = x4[2 * i + 1];
    a.x = a.x * scale + off; a.y = a.y * scale + off;
    a.z = a.z * scale + off; a.w = a.w * scale + off;
    b.x = b.x * scale + off; b.y = b.y * scale + off;
    b.z = b.z * scale + off; b.w = b.w * scale + off;
    x4[2 * i] = a;
    x4[2 * i + 1] = b;
}

extern "C" void kernel_launch(void* const* d_in, const int* in_sizes, int n_in,
                              void* d_out, int out_size, void* d_ws, size_t ws_size,
                              hipStream_t stream) {
    const float* X   = (const float*)d_in[0];
    const int*   edg = (const int*)d_in[1];   // [2,E]: src row then dst row
    const float* W1  = (const float*)d_in[2];
    const float* b1  = (const float*)d_in[3];
    const float* W2  = (const float*)d_in[4];
    const float* b2  = (const float*)d_in[5];
    const float* lnw = (const float*)d_in[6];
    const float* lnb = (const float*)d_in[7];
    float* out = (float*)d_out;

    const int N  = in_sizes[0] / CH;   // 100000
    const int E  = in_sizes[1] / 2;    // 1600000
    const int NC = N * CH;             // 6.4M
    const int nNodeBlk = (N + 3) / 4;  // 25000 (4 nodes / block)
    const int nb = (N + 511) >> BSH;   // 196 buckets
    const int nblkE = (E + CHUNK - 1) / CHUNK;  // 98 edge-chunk blocks

    const int* srcp = edg;
    const int* dstp = edg + E;

    // workspace layout (4B units).  ALIGNMENT RULE (R12): rs padded to N+32
    // so dis/xws1/xws2/h stay 128B-aligned.  pairs = nb*MAXCAP u32 (12.85MB)
    // overlays h (25.6MB; dead before h live).  bucketCnt line-padded (x16).
    int*   col   = (int*)d_ws;                          // E (aligned)
    int*   rs    = col + E;                             // N+1 used, N+32 reserved
    float* dis   = (float*)(rs + N + 32);               // N (aligned)
    __hip_bfloat16* xws1 = (__hip_bfloat16*)(dis + N);  // NC bf16 (128B rows)
    __hip_bfloat16* xws2 = xws1 + NC;                   // NC bf16 (128B rows)
    float* h     = (float*)(xws2 + NC);                 // NC floats (256B rows)
    unsigned* pairs = (unsigned*)h;                     // nb*MAXCAP u32
    int*   bucketCnt = (int*)(h + NC);                  // nb*16 (line-padded)
    float* sums  = (float*)(bucketCnt + 224 * 16);      // nNodeBlk (224*16: pad, x32 mult)
    float* sqs   = sums + nNodeBlk;                     // nNodeBlk
    float* so    = sqs + nNodeBlk;                      // 2 {scale, offset}

    const int B = 256;
    const int nGemmBlk = (N + 127) / 128;               // 782 (4 rows/thread)

    // ---- CSR build: 3 regular kernels ----
    zero_cnt_kernel<<<4, 1024, 0, stream>>>(bucketCnt, nb * 16);
    scatter_direct_kernel<<<nblkE, 1024, 0, stream>>>(srcp, dstp, bucketCnt, pairs, E, nb);
    bucket_direct_kernel<<<nb, 1024, 0, stream>>>(pairs, bucketCnt, col, rs, dis, N, nb, E);
    // rs = row_start; row i spans [rs[i], rs[i+1]); rs[N] = E

    // ---- layer 1 ----
    gemm64_scaled_kernel<<<nGemmBlk, B, 0, stream>>>(X, W1, dis, xws1, N);
    gather_pair_kernel<<<nNodeBlk, B, 0, stream>>>((const unsigned*)xws1, col, rs, dis,
                                                   b1, h, N, E);

    // ---- layer 2 ----
    gemm64_scaled_kernel<<<nGemmBlk, B, 0, stream>>>(h, W2, dis, xws2, N);
    gather_stats_kernel<<<nNodeBlk, B, 0, stream>>>((const unsigned*)xws2, col, rs, dis,
                                                    b2, out, N, E, sums, sqs);

    // ---- graph layernorm ----
    reduce_final_kernel<<<1, 1024, 0, stream>>>(sums, sqs, nNodeBlk, (float)NC, lnw, lnb, so);
    norm_kernel<<<(NC / 8 + B - 1) / B, B, 0, stream>>>(out, NC / 8, so);
}